// Round 7
// baseline (2478.020 us; speedup 1.0000x reference)
//
#include <hip/hip_runtime.h>

#define HW 3136
#define NB 32
#define NC 128

__global__ __launch_bounds__(256, 4)
void mvg_kernel(const float* __restrict__ emb, float* __restrict__ out) {
  // XCD-bijective swizzle (3136 = 8*392): contiguous pos chunk per XCD.
  const int bid = blockIdx.x;
  const int pos = (bid & 7) * 392 + (bid >> 3);
  const int t = threadIdx.x;
  const int rm = t >> 4;
  const int cm = t & 15;
  const int i0 = rm << 3;
  const int c0 = cm << 3;

  __shared__ float Xs[NB * NC];                    // dense 16 KB slice
  __shared__ __align__(16) float hbuf[2][132];     // encoded pivot row h
  __shared__ __align__(16) float gbuf[2][132];     // pre-scaled row g = h/d
  __shared__ float ms[NC];

  // ---- gather the (B, C) slice ----
  #pragma unroll
  for (int m = 0; m < 16; ++m) {
    const int idx = t + 256 * m;
    const int b = idx >> 7;
    const int c = idx & (NC - 1);
    Xs[idx] = emb[(size_t)b * ((size_t)NC * HW) + (size_t)c * HW + pos];
  }
  __syncthreads();

  // ---- mean over batch, write mean output ----
  if (t < NC) {
    float s = 0.f;
    #pragma unroll
    for (int b = 0; b < NB; ++b) s += Xs[b * NC + t];
    const float m = s * (1.0f / NB);
    ms[t] = m;
    out[(size_t)t * HW + pos] = m;
  }
  __syncthreads();

  // ---- center ----
  #pragma unroll
  for (int m = 0; m < 16; ++m) {
    const int idx = t + 256 * m;
    Xs[idx] -= ms[idx & (NC - 1)];
  }
  __syncthreads();

  float4 a0[8], a1[8];
  #pragma unroll
  for (int r = 0; r < 8; ++r) {
    a0[r] = make_float4(0.f, 0.f, 0.f, 0.f);
    a1[r] = make_float4(0.f, 0.f, 0.f, 0.f);
  }

  // ---- covariance accumulate ----
  for (int b = 0; b < NB; ++b) {
    const float* xr = &Xs[b * NC];
    const float4 rv0 = *(const float4*)&xr[c0];
    const float4 rv1 = *(const float4*)&xr[c0 + 4];
    const float4 cv0 = *(const float4*)&xr[i0];
    const float4 cv1 = *(const float4*)&xr[i0 + 4];
    const float cr[8] = {cv0.x, cv0.y, cv0.z, cv0.w, cv1.x, cv1.y, cv1.z, cv1.w};
    #pragma unroll
    for (int r = 0; r < 8; ++r) {
      a0[r].x = fmaf(cr[r], rv0.x, a0[r].x);
      a0[r].y = fmaf(cr[r], rv0.y, a0[r].y);
      a0[r].z = fmaf(cr[r], rv0.z, a0[r].z);
      a0[r].w = fmaf(cr[r], rv0.w, a0[r].w);
      a1[r].x = fmaf(cr[r], rv1.x, a1[r].x);
      a1[r].y = fmaf(cr[r], rv1.y, a1[r].y);
      a1[r].z = fmaf(cr[r], rv1.z, a1[r].z);
      a1[r].w = fmaf(cr[r], rv1.w, a1[r].w);
    }
  }

  // ---- scale 1/(B-1), + (REG_DIAG+REG_EPS) I ----
  {
    const float s31 = 1.0f / (float)(NB - 1);
    const float RD = 0.01f + 1e-5f;
    #pragma unroll
    for (int r = 0; r < 8; ++r) {
      const int gr = i0 + r;
      a0[r].x = a0[r].x * s31 + ((gr == c0 + 0) ? RD : 0.f);
      a0[r].y = a0[r].y * s31 + ((gr == c0 + 1) ? RD : 0.f);
      a0[r].z = a0[r].z * s31 + ((gr == c0 + 2) ? RD : 0.f);
      a0[r].w = a0[r].w * s31 + ((gr == c0 + 3) ? RD : 0.f);
      a1[r].x = a1[r].x * s31 + ((gr == c0 + 4) ? RD : 0.f);
      a1[r].y = a1[r].y * s31 + ((gr == c0 + 5) ? RD : 0.f);
      a1[r].z = a1[r].z * s31 + ((gr == c0 + 6) ? RD : 0.f);
      a1[r].w = a1[r].w * s31 + ((gr == c0 + 7) ? RD : 0.f);
    }
  }

  // ---- prologue: publish h_0 = row0 - e0 (slot 0 = d-1) and g_0 = h_0/d ----
  if (rm == 0) {
    const float d0 = __shfl(a0[0].x, 0, 16);     // raw diagonal, lane cm=0
    const float rd0 = __builtin_amdgcn_rcpf(d0);
    float4 t0 = a0[0], t1 = a1[0];
    if (cm == 0) t0.x -= 1.0f;
    *(float4*)&hbuf[0][c0] = t0;
    *(float4*)&hbuf[0][c0 + 4] = t1;
    float4 g0, g1;
    g0.x = t0.x * rd0; g0.y = t0.y * rd0; g0.z = t0.z * rd0; g0.w = t0.w * rd0;
    g1.x = t1.x * rd0; g1.y = t1.y * rd0; g1.z = t1.z * rd0; g1.w = t1.w * rd0;
    *(float4*)&gbuf[0][c0] = g0;
    *(float4*)&gbuf[0][c0 + 4] = g1;
  }
  __syncthreads();

  // initial prefetch (reg set A) for pivot 0
  float4 hrA0 = *(const float4*)&hbuf[0][c0];
  float4 hrA1 = *(const float4*)&hbuf[0][c0 + 4];
  float4 gcA0 = *(const float4*)&gbuf[0][i0];
  float4 gcA1 = *(const float4*)&gbuf[0][i0 + 4];
  float gokA = gbuf[0][1];
  float4 hrB0, hrB1, gcB0, gcB1;
  float gokB;

  // One step for pivot P:
  //  owner (rm==OWNRM, static LR = kk - 8*OWNRM) computes row kk updated by
  //  pivot P with coefficient cok = -g_P[kk] (preloaded), encodes -1 at the
  //  static diag component TD, shfl-broadcasts the new (d-1), builds
  //  g = h * rcp(d), publishes both BEFORE the barrier. After the barrier all
  //  threads prefetch step P+1 data, then bulk-update:
  //  a[r] -= g_P[i0+r] * h_P  (exact R1 arithmetic, h-encoding incl. pivot row).
  #define STEP(P, CUR, NXT, OWNRM, LR, TR, TC,                              \
               HR0, HR1, GC0, GC1, GOK, NHR0, NHR1, NGC0, NGC1, NGOK) {     \
    const int kk = (P) + 1;                                                 \
    if (rm == (OWNRM)) {                                                    \
      const float cok = -(GOK);                                             \
      float4 t0, t1;                                                        \
      t0.x = fmaf(cok, HR0.x, a0[LR].x);                                    \
      t0.y = fmaf(cok, HR0.y, a0[LR].y);                                    \
      t0.z = fmaf(cok, HR0.z, a0[LR].z);                                    \
      t0.w = fmaf(cok, HR0.w, a0[LR].w);                                    \
      t1.x = fmaf(cok, HR1.x, a1[LR].x);                                    \
      t1.y = fmaf(cok, HR1.y, a1[LR].y);                                    \
      t1.z = fmaf(cok, HR1.z, a1[LR].z);                                    \
      t1.w = fmaf(cok, HR1.w, a1[LR].w);                                    \
      const int kh = kk >> 3;                                               \
      if (cm == kh) TR.TC -= 1.0f;                                          \
      const float tde = __shfl(TR.TC, kh, 16);                              \
      const float rd1 = __builtin_amdgcn_rcpf(tde + 1.0f);                  \
      float4 g0, g1;                                                        \
      g0.x = t0.x * rd1; g0.y = t0.y * rd1;                                 \
      g0.z = t0.z * rd1; g0.w = t0.w * rd1;                                 \
      g1.x = t1.x * rd1; g1.y = t1.y * rd1;                                 \
      g1.z = t1.z * rd1; g1.w = t1.w * rd1;                                 \
      *(float4*)&hbuf[NXT][c0] = t0;                                        \
      *(float4*)&hbuf[NXT][c0 + 4] = t1;                                    \
      *(float4*)&gbuf[NXT][c0] = g0;                                        \
      *(float4*)&gbuf[NXT][c0 + 4] = g1;                                    \
    }                                                                       \
    __syncthreads();                                                        \
    NHR0 = *(const float4*)&hbuf[NXT][c0];                                  \
    NHR1 = *(const float4*)&hbuf[NXT][c0 + 4];                              \
    NGC0 = *(const float4*)&gbuf[NXT][i0];                                  \
    NGC1 = *(const float4*)&gbuf[NXT][i0 + 4];                              \
    NGOK = gbuf[NXT][kk + 1];                                               \
    {                                                                       \
      const float cr[8] = {GC0.x, GC0.y, GC0.z, GC0.w,                      \
                           GC1.x, GC1.y, GC1.z, GC1.w};                     \
      _Pragma("unroll")                                                     \
      for (int r = 0; r < 8; ++r) {                                         \
        a0[r].x = fmaf(-cr[r], HR0.x, a0[r].x);                             \
        a0[r].y = fmaf(-cr[r], HR0.y, a0[r].y);                             \
        a0[r].z = fmaf(-cr[r], HR0.z, a0[r].z);                             \
        a0[r].w = fmaf(-cr[r], HR0.w, a0[r].w);                             \
        a1[r].x = fmaf(-cr[r], HR1.x, a1[r].x);                             \
        a1[r].y = fmaf(-cr[r], HR1.y, a1[r].y);                             \
        a1[r].z = fmaf(-cr[r], HR1.z, a1[r].z);                             \
        a1[r].w = fmaf(-cr[r], HR1.w, a1[r].w);                             \
      }                                                                     \
    }                                                                       \
  }

  // ---- 128 pivots: 16 iterations x 8 static steps ----
  #pragma unroll 1
  for (int q = 0; q < 16; ++q) {
    const int k0 = q << 3;
    STEP(k0 + 0, 0, 1, q,     1, t0, y, hrA0, hrA1, gcA0, gcA1, gokA,
         hrB0, hrB1, gcB0, gcB1, gokB)
    STEP(k0 + 1, 1, 0, q,     2, t0, z, hrB0, hrB1, gcB0, gcB1, gokB,
         hrA0, hrA1, gcA0, gcA1, gokA)
    STEP(k0 + 2, 0, 1, q,     3, t0, w, hrA0, hrA1, gcA0, gcA1, gokA,
         hrB0, hrB1, gcB0, gcB1, gokB)
    STEP(k0 + 3, 1, 0, q,     4, t1, x, hrB0, hrB1, gcB0, gcB1, gokB,
         hrA0, hrA1, gcA0, gcA1, gokA)
    STEP(k0 + 4, 0, 1, q,     5, t1, y, hrA0, hrA1, gcA0, gcA1, gokA,
         hrB0, hrB1, gcB0, gcB1, gokB)
    STEP(k0 + 5, 1, 0, q,     6, t1, z, hrB0, hrB1, gcB0, gcB1, gokB,
         hrA0, hrA1, gcA0, gcA1, gokA)
    STEP(k0 + 6, 0, 1, q,     7, t1, w, hrA0, hrA1, gcA0, gcA1, gokA,
         hrB0, hrB1, gcB0, gcB1, gokB)
    STEP(k0 + 7, 1, 0, q + 1, 0, t0, x, hrB0, hrB1, gcB0, gcB1, gokB,
         hrA0, hrA1, gcA0, gcA1, gokA)
  }

  // ---- store: inv = -reg, diag = 2 - reg (undo the +2 encoding artifact) ----
  float* o = out + (size_t)NC * HW + (size_t)pos * (NC * NC);
  #pragma unroll
  for (int r = 0; r < 8; ++r) {
    const int gr = i0 + r;
    float4 w0, w1;
    w0.x = (gr == c0 + 0) ? (2.0f - a0[r].x) : (-a0[r].x);
    w0.y = (gr == c0 + 1) ? (2.0f - a0[r].y) : (-a0[r].y);
    w0.z = (gr == c0 + 2) ? (2.0f - a0[r].z) : (-a0[r].z);
    w0.w = (gr == c0 + 3) ? (2.0f - a0[r].w) : (-a0[r].w);
    w1.x = (gr == c0 + 4) ? (2.0f - a1[r].x) : (-a1[r].x);
    w1.y = (gr == c0 + 5) ? (2.0f - a1[r].y) : (-a1[r].y);
    w1.z = (gr == c0 + 6) ? (2.0f - a1[r].z) : (-a1[r].z);
    w1.w = (gr == c0 + 7) ? (2.0f - a1[r].w) : (-a1[r].w);
    *(float4*)&o[(size_t)gr * NC + c0] = w0;
    *(float4*)&o[(size_t)gr * NC + c0 + 4] = w1;
  }
}

extern "C" void kernel_launch(void* const* d_in, const int* in_sizes, int n_in,
                              void* d_out, int out_size, void* d_ws, size_t ws_size,
                              hipStream_t stream) {
  const float* emb = (const float*)d_in[0];
  float* out = (float*)d_out;
  mvg_kernel<<<HW, 256, 0, stream>>>(emb, out);
}